// Round 11
// baseline (282.032 us; speedup 1.0000x reference)
//
#include <hip/hip_runtime.h>
#include <hip/hip_bf16.h>

#define SCALE 0.1767766952966369f  // (256/8)^-0.5

typedef unsigned short bfu;
typedef unsigned int u32;
typedef __attribute__((ext_vector_type(8))) short bf8v;      // MFMA A/B frag (8 bf16)
typedef __attribute__((ext_vector_type(4))) float f32x4;     // MFMA C/D frag
typedef __attribute__((ext_vector_type(8))) unsigned short u16x8;
typedef __attribute__((ext_vector_type(4))) unsigned int u32x4;

__device__ __forceinline__ bfu f2b(float x) {
    __hip_bfloat16 h = __float2bfloat16(x);
    return *(bfu*)&h;
}
__device__ __forceinline__ float bu2f(bfu u) {
    return __uint_as_float(((unsigned int)u) << 16);
}
__device__ __forceinline__ u32 cvtpk(float lo, float hi) {
    u32 r;
    asm("v_cvt_pk_bf16_f32 %0, %1, %2" : "=v"(r) : "v"(lo), "v"(hi));
    return r;
}
__device__ __forceinline__ void gload16(const bfu* g, bfu* l) {
    __builtin_amdgcn_global_load_lds(
        (const __attribute__((address_space(1))) unsigned int*)g,
        (__attribute__((address_space(3))) unsigned int*)l, 16, 0, 0);
}

// ---------------- prep: fmap fp32 NCHW -> bf16 NHWC ----------------
__global__ __launch_bounds__(256) void k_prep_f(const float* __restrict__ fmap,
                                                bfu* __restrict__ Fbf) {
    const int x = blockIdx.x, b = blockIdx.y;
    const int t = threadIdx.x;
    __shared__ float tile[64][69];
    for (int cc = 0; cc < 256; cc += 64) {
        #pragma unroll
        for (int i = 0; i < 4; ++i) {
            const int c = (t >> 4) + i * 16, y4 = (t & 15) * 4;
            const float4 v = *(const float4*)(fmap + (((size_t)b * 256 + cc + c) * 64 + x) * 64 + y4);
            tile[y4][c] = v.x; tile[y4 + 1][c] = v.y; tile[y4 + 2][c] = v.z; tile[y4 + 3][c] = v.w;
        }
        __syncthreads();
        const int y = t >> 2, cs = (t & 3) * 16;
        u16x8 o0, o1;
        #pragma unroll
        for (int j = 0; j < 8; ++j) { o0[j] = f2b(tile[y][cs + j]); o1[j] = f2b(tile[y][cs + 8 + j]); }
        bfu* dst = Fbf + (((size_t)b * 64 + x) * 64 + y) * 256 + cc + cs;
        *(u16x8*)dst = o0; *(u16x8*)(dst + 8) = o1;
        __syncthreads();
    }
}

// ---------------- prep: weights -> bf16 (Wkl stacked; qv reordered r'=kh*128+c) ----------------
__global__ __launch_bounds__(256) void k_prep_w(
    const float* __restrict__ Wk, const float* __restrict__ Wl,
    const float* __restrict__ Wh, const float* __restrict__ Wv,
    bfu* __restrict__ Wkl, bfu* __restrict__ Whr, bfu* __restrict__ Wvr) {
    const int i = blockIdx.x * 256 + threadIdx.x;   // 0..131071
    {
        const int o = i >> 8;
        Wkl[i] = f2b((o < 256) ? Wk[i] : Wl[i - 65536]);
    }
    if (i < 65536) {
        const int o = i >> 8, r = i & 255, kh = r >> 7, c = r & 127;
        const int s = (o * 128 + c) * 2 + kh;
        Whr[i] = f2b(Wh[s]);
        Wvr[i] = f2b(Wv[s]);
    }
}

// ---------------- ALL projection GEMMs in ONE dispatch ----------------
// 4096 blocks (1D), 512 threads, 128x128 tile, K=256, 64 KB LDS.
// bid < 2048          : mode 0  k_all+lepe (A=Wkl, M=512 via mt=0..3)
// 2048 <= bid < 3072  : mode 1  qv_h (A=Whr, mt=0..1)
// 3072 <= bid         : mode 2  qv_v (A=Wvr, mt=0..1)
// Independent outputs -> single dispatch lets all three overlap (latency fill).
// B staged via global_load_lds(16B), XOR chunk-swizzle c'=c^(row&7) on the
// per-lane GLOBAL source addr and the same XOR on the ds_read_b128 addr.
__global__ __launch_bounds__(512) void k_gemm_all(
    const bfu* __restrict__ Wkl, const bfu* __restrict__ Whr,
    const bfu* __restrict__ Wvr, const bfu* __restrict__ Bsrc,
    bfu* __restrict__ o_kall, bfu* __restrict__ o_lepe,
    bfu* __restrict__ o_qvh, bfu* __restrict__ o_qvv) {
    const int bid = blockIdx.x;
    int mode, nt, mt, b;
    if (bid < 2048) {
        mode = 0; nt = bid & 31; mt = (bid >> 5) & 3; b = bid >> 7;
    } else {
        int i = bid - 2048;
        mode = 1 + (i >> 10); i &= 1023;
        nt = i & 15; mt = (i >> 4) & 1; b = i >> 5;
    }
    const int n0 = nt * 128, m0 = mt * 128;
    const int t = threadIdx.x, lane = t & 63;
    const int wave = t >> 6;                   // 0..7
    const int wm = wave >> 1, wn = wave & 1;   // wm 0..3 (M 32), wn 0..1 (N 64)
    const int lq = lane >> 4, lr = lane & 15;
    __shared__ bfu Bs[128 * 256];               // linear, 64 KB
    const bfu* fb = Bsrc + (size_t)b * 1048576;  // 4096 spatial * 256 ch
    const bfu* A = (mode == 0) ? Wkl : ((mode == 1) ? Whr : Wvr);

    // ---- stage: 16 rows per wave; one gload16 covers 2 rows (64 lanes x 16B)
    {
        const int lrow = lane >> 5;
        const int c1 = lane & 31;
        #pragma unroll
        for (int i = 0; i < 8; ++i) {
            const int row = wave * 16 + i * 2 + lrow;
            const int cS = c1 ^ (row & 7);      // source chunk (inverse swizzle)
            int so;
            if (mode == 0) {
                so = (n0 + row) * 256 + cS * 8;
            } else if (mode == 1) {
                const int n = n0 + row;
                const int xo = n >> 6, y = n & 63;
                so = ((2 * xo + (cS >> 4)) * 64 + y) * 256 + (cS & 15) * 8;
            } else {
                const int n = n0 + row;
                const int x = n >> 5, yo = n & 31;
                so = (x * 64 + 2 * yo + (cS >> 4)) * 256 + 128 + (cS & 15) * 8;
            }
            gload16(fb + so, Bs + (wave * 16 + i * 2) * 256);
        }
    }
    __syncthreads();

    f32x4 acc[2][4];
    #pragma unroll
    for (int mi = 0; mi < 2; ++mi)
        #pragma unroll
        for (int ni = 0; ni < 4; ++ni) {
            acc[mi][ni][0] = 0.f; acc[mi][ni][1] = 0.f; acc[mi][ni][2] = 0.f; acc[mi][ni][3] = 0.f;
        }

    #pragma unroll
    for (int k0 = 0; k0 < 8; ++k0) {
        bf8v af[2], bv[4];
        #pragma unroll
        for (int mi = 0; mi < 2; ++mi)
            af[mi] = *(const bf8v*)(A + (size_t)(m0 + wm * 32 + mi * 16 + lr) * 256 + k0 * 32 + lq * 8);
        #pragma unroll
        for (int ni = 0; ni < 4; ++ni) {
            const int row = wn * 64 + ni * 16 + lr;
            const int ck = (k0 * 4 + lq) ^ (row & 7);   // swizzled read chunk
            bv[ni] = *(const bf8v*)(Bs + row * 256 + ck * 8);
        }
        #pragma unroll
        for (int mi = 0; mi < 2; ++mi)
            #pragma unroll
            for (int ni = 0; ni < 4; ++ni)
                acc[mi][ni] = __builtin_amdgcn_mfma_f32_16x16x32_bf16(af[mi], bv[ni], acc[mi][ni], 0, 0, 0);
    }

    // epilogue: D[m][n], m-row = (lane>>4)*4+reg, n-col = lane&15
    if (mode == 0) {
        bfu* outp = (mt < 2) ? o_kall : o_lepe;
        const int chb = (mt & 1) * 128 + wm * 32;
        #pragma unroll
        for (int mi = 0; mi < 2; ++mi)
            #pragma unroll
            for (int ni = 0; ni < 4; ++ni) {
                const int ch = chb + mi * 16 + lq * 4;
                const int ng = n0 + wn * 64 + ni * 16 + lr;
                ushort4 pk;
                pk.x = f2b(acc[mi][ni][0]); pk.y = f2b(acc[mi][ni][1]);
                pk.z = f2b(acc[mi][ni][2]); pk.w = f2b(acc[mi][ni][3]);
                *(ushort4*)(outp + ((size_t)b * 4096 + ng) * 256 + ch) = pk;
            }
    } else {
        bfu* outp = (mode == 1) ? o_qvh : o_qvv;
        #pragma unroll
        for (int mi = 0; mi < 2; ++mi)
            #pragma unroll
            for (int ni = 0; ni < 4; ++ni) {
                const int ch = m0 + wm * 32 + mi * 16 + lq * 4;
                const int ng = n0 + wn * 64 + ni * 16 + lr;
                ushort4 pk;
                pk.x = f2b(acc[mi][ni][0]); pk.y = f2b(acc[mi][ni][1]);
                pk.z = f2b(acc[mi][ni][2]); pk.w = f2b(acc[mi][ni][3]);
                *(ushort4*)(outp + ((size_t)b * 2048 + ng) * 256 + ch) = pk;
            }
    }
}

// ---------------- proj: out = fmap + W_proj @ cat (fp32 A on the fly) ----------------
__global__ __launch_bounds__(512) void k_proj(
    const float* __restrict__ Af32, const bfu* __restrict__ Bsrc,
    const float* __restrict__ resid, float* __restrict__ outf) {
    const int nt = blockIdx.x, mt = blockIdx.y, b = blockIdx.z;
    const int n0 = nt * 128, m0 = mt * 128;
    const int t = threadIdx.x, lane = t & 63;
    const int wave = t >> 6;
    const int wm = wave >> 1, wn = wave & 1;
    const int lq = lane >> 4, lr = lane & 15;
    __shared__ bfu Bs[128 * 256];
    const bfu* fb = Bsrc + (size_t)b * 1048576;

    {
        const int lrow = lane >> 5, c1 = lane & 31;
        #pragma unroll
        for (int i = 0; i < 8; ++i) {
            const int row = wave * 16 + i * 2 + lrow;
            const int cS = c1 ^ (row & 7);
            gload16(fb + (n0 + row) * 256 + cS * 8, Bs + (wave * 16 + i * 2) * 256);
        }
    }
    __syncthreads();

    f32x4 acc[2][4];
    #pragma unroll
    for (int mi = 0; mi < 2; ++mi)
        #pragma unroll
        for (int ni = 0; ni < 4; ++ni) {
            acc[mi][ni][0] = 0.f; acc[mi][ni][1] = 0.f; acc[mi][ni][2] = 0.f; acc[mi][ni][3] = 0.f;
        }

    #pragma unroll
    for (int k0 = 0; k0 < 8; ++k0) {
        bf8v af[2], bv[4];
        #pragma unroll
        for (int mi = 0; mi < 2; ++mi) {
            const float* ap = Af32 + (size_t)(m0 + wm * 32 + mi * 16 + lr) * 256 + k0 * 32 + lq * 8;
            const float4 u0 = *(const float4*)ap;
            const float4 u1 = *(const float4*)(ap + 4);
            bf8v a;
            a[0] = (short)f2b(u0.x); a[1] = (short)f2b(u0.y);
            a[2] = (short)f2b(u0.z); a[3] = (short)f2b(u0.w);
            a[4] = (short)f2b(u1.x); a[5] = (short)f2b(u1.y);
            a[6] = (short)f2b(u1.z); a[7] = (short)f2b(u1.w);
            af[mi] = a;
        }
        #pragma unroll
        for (int ni = 0; ni < 4; ++ni) {
            const int row = wn * 64 + ni * 16 + lr;
            const int ck = (k0 * 4 + lq) ^ (row & 7);
            bv[ni] = *(const bf8v*)(Bs + row * 256 + ck * 8);
        }
        #pragma unroll
        for (int mi = 0; mi < 2; ++mi)
            #pragma unroll
            for (int ni = 0; ni < 4; ++ni)
                acc[mi][ni] = __builtin_amdgcn_mfma_f32_16x16x32_bf16(af[mi], bv[ni], acc[mi][ni], 0, 0, 0);
    }

    #pragma unroll
    for (int mi = 0; mi < 2; ++mi)
        #pragma unroll
        for (int ni = 0; ni < 4; ++ni) {
            const int ng = n0 + wn * 64 + ni * 16 + lr;
            #pragma unroll
            for (int r = 0; r < 4; ++r) {
                const int m = m0 + wm * 32 + mi * 16 + lq * 4 + r;
                const size_t ad = ((size_t)b * 256 + m) * 4096 + ng;
                outf[ad] = resid[ad] + acc[mi][ni][r];
            }
        }
}

// ---------------- MFMA attention, BOTH branches in one dispatch ----------------
// 4096 blocks: BR = bid>>11 (runtime, block-uniform). Within each half, h in
// HIGH bits so all 8 heads (and both branches) of a window share bid%8 (XCD).
// No max-subtraction in softmax (|S*SCALE| <~ 1; softmax shift-invariant).
__global__ __launch_bounds__(256) void k_attn(
    const bfu* __restrict__ Qh, const bfu* __restrict__ Qvv,
    const bfu* __restrict__ Kb, const bfu* __restrict__ Lp,
    bfu* __restrict__ cat) {
    const int bid = blockIdx.x;
    const int BR = bid >> 11;
    const int bl = bid & 2047;
    const int h = (bl >> 8) & 7;
    const int bg = bl & 255;
    const int b = bg >> 4, g = bg & 15;
    const int t = threadIdx.x, lane = t & 63, w = t >> 6;
    const int lr = lane & 15, lq = lane >> 4;
    const int chQ = h * 16, chV = 128 + h * 16;
    const int chO = (BR == 0) ? h * 16 : 128 + h * 16;
    const bfu* Qb = ((BR == 0) ? Qh : Qvv) + (size_t)b * 2048 * 256;
    const bfu* Kg = Kb + (size_t)b * 4096 * 256 + chO;
    const bfu* Lg = Lp + (size_t)b * 4096 * 256 + chO;
    bfu* Cg = cat + (size_t)b * 4096 * 256 + chO;

    __shared__ float psum[2][256];  // [gq][wave*64 + q]

    bf8v kf[4];
    #pragma unroll
    for (int ct = 0; ct < 4; ++ct) {
        const int ktok = (4 * w + ct) * 16 + lr;
        const int sp = (BR == 0) ? ((ktok >> 2) * 64 + g * 4 + (ktok & 3))
                                 : ((g * 4 + (ktok >> 6)) * 64 + (ktok & 63));
        if (lq < 2) kf[ct] = *(const bf8v*)(Kg + (size_t)sp * 256 + lq * 8);
        else        kf[ct] = bf8v{0, 0, 0, 0, 0, 0, 0, 0};
    }

    f32x4 oacc[4];
    #pragma unroll
    for (int ct = 0; ct < 4; ++ct) { oacc[ct][0] = 0.f; oacc[ct][1] = 0.f; oacc[ct][2] = 0.f; oacc[ct][3] = 0.f; }

    for (int gq = 0; gq < 2; ++gq) {
        bf8v qf[4];
        #pragma unroll
        for (int qt = 0; qt < 4; ++qt) {
            const int qtok = gq * 64 + qt * 16 + lr;
            const int sp = (BR == 0) ? ((qtok >> 2) * 64 + g * 4 + (qtok & 3))
                                     : ((g * 4 + (qtok >> 5)) * 32 + (qtok & 31));
            if (lq < 2) qf[qt] = *(const bf8v*)(Qb + (size_t)sp * 256 + chQ + lq * 8);
            else        qf[qt] = bf8v{0, 0, 0, 0, 0, 0, 0, 0};
        }
        bf8v vf[2];
        #pragma unroll
        for (int c = 0; c < 2; ++c) {
            #pragma unroll
            for (int j = 0; j < 8; ++j) {
                const int qtok = gq * 64 + c * 32 + lq * 8 + j;
                const int sp = (BR == 0) ? ((qtok >> 2) * 64 + g * 4 + (qtok & 3))
                                         : ((g * 4 + (qtok >> 5)) * 32 + (qtok & 31));
                vf[c][j] = (short)Qb[(size_t)sp * 256 + chV + lr];
            }
        }

        f32x4 acc[4][4];
        #pragma unroll
        for (int qt = 0; qt < 4; ++qt)
            #pragma unroll
            for (int ct = 0; ct < 4; ++ct) {
                acc[qt][ct][0] = 0.f; acc[qt][ct][1] = 0.f; acc[qt][ct][2] = 0.f; acc[qt][ct][3] = 0.f;
            }
        #pragma unroll
        for (int qt = 0; qt < 4; ++qt)
            #pragma unroll
            for (int ct = 0; ct < 4; ++ct)
                acc[qt][ct] = __builtin_amdgcn_mfma_f32_16x16x32_bf16(qf[qt], kf[ct], acc[qt][ct], 0, 0, 0);

        #pragma unroll
        for (int qt = 0; qt < 4; ++qt)
            #pragma unroll
            for (int ct = 0; ct < 4; ++ct)
                #pragma unroll
                for (int r = 0; r < 4; ++r)
                    acc[qt][ct][r] = __expf(acc[qt][ct][r] * SCALE);

        float rr[4][4];
        #pragma unroll
        for (int qt = 0; qt < 4; ++qt)
            #pragma unroll
            for (int r = 0; r < 4; ++r)
                rr[qt][r] = (acc[qt][0][r] + acc[qt][1][r]) + (acc[qt][2][r] + acc[qt][3][r]);
        #pragma unroll
        for (int s = 1; s <= 8; s <<= 1)
            #pragma unroll
            for (int qt = 0; qt < 4; ++qt)
                #pragma unroll
                for (int r = 0; r < 4; ++r)
                    rr[qt][r] += __shfl_xor(rr[qt][r], s);
        if (lr == 0) {
            #pragma unroll
            for (int qt = 0; qt < 4; ++qt)
                #pragma unroll
                for (int r = 0; r < 4; ++r)
                    psum[gq][w * 64 + qt * 16 + lq * 4 + r] = rr[qt][r];
        }
        __syncthreads();
        float inv[4][4];
        #pragma unroll
        for (int qt = 0; qt < 4; ++qt)
            #pragma unroll
            for (int r = 0; r < 4; ++r) {
                const int qi = qt * 16 + lq * 4 + r;
                inv[qt][r] = 1.0f / ((psum[gq][qi] + psum[gq][64 + qi]) +
                                     (psum[gq][128 + qi] + psum[gq][192 + qi]));
            }

        u32 pk[4][4][2];
        #pragma unroll
        for (int qt = 0; qt < 4; ++qt)
            #pragma unroll
            for (int ct = 0; ct < 4; ++ct) {
                pk[qt][ct][0] = cvtpk(acc[qt][ct][0] * inv[qt][0], acc[qt][ct][1] * inv[qt][1]);
                pk[qt][ct][1] = cvtpk(acc[qt][ct][2] * inv[qt][2], acc[qt][ct][3] * inv[qt][3]);
            }

        const int base = ((lane >> 4) & 1) * 32 + (lane & 15);
        const bool hi = (lq >= 2);
        #pragma unroll
        for (int c = 0; c < 2; ++c) {
            #pragma unroll
            for (int ct = 0; ct < 4; ++ct) {
                const u32 a0 = (u32)__shfl((int)pk[2 * c][ct][0], base);
                const u32 a1 = (u32)__shfl((int)pk[2 * c][ct][1], base);
                const u32 a2 = (u32)__shfl((int)pk[2 * c][ct][0], base + 16);
                const u32 a3 = (u32)__shfl((int)pk[2 * c][ct][1], base + 16);
                const u32 b0 = (u32)__shfl((int)pk[2 * c + 1][ct][0], base);
                const u32 b1 = (u32)__shfl((int)pk[2 * c + 1][ct][1], base);
                const u32 b2 = (u32)__shfl((int)pk[2 * c + 1][ct][0], base + 16);
                const u32 b3 = (u32)__shfl((int)pk[2 * c + 1][ct][1], base + 16);
                u32x4 wd;
                wd[0] = hi ? b0 : a0; wd[1] = hi ? b1 : a1;
                wd[2] = hi ? b2 : a2; wd[3] = hi ? b3 : a3;
                const bf8v pf = __builtin_bit_cast(bf8v, wd);
                oacc[ct] = __builtin_amdgcn_mfma_f32_16x16x32_bf16(vf[c], pf, oacc[ct], 0, 0, 0);
            }
        }
    }

    #pragma unroll
    for (int ct = 0; ct < 4; ++ct) {
        const int ktok = (4 * w + ct) * 16 + lr;
        const int sp = (BR == 0) ? ((ktok >> 2) * 64 + g * 4 + (ktok & 3))
                                 : ((g * 4 + (ktok >> 6)) * 64 + (ktok & 63));
        const size_t off = (size_t)sp * 256 + lq * 4;
        const ushort4 l4 = *(const ushort4*)(Lg + off);
        ushort4 o;
        o.x = f2b(oacc[ct][0] + bu2f(l4.x));
        o.y = f2b(oacc[ct][1] + bu2f(l4.y));
        o.z = f2b(oacc[ct][2] + bu2f(l4.z));
        o.w = f2b(oacc[ct][3] + bu2f(l4.w));
        *(ushort4*)(Cg + off) = o;
    }
}

extern "C" void kernel_launch(void* const* d_in, const int* in_sizes, int n_in,
                              void* d_out, int out_size, void* d_ws, size_t ws_size,
                              hipStream_t stream) {
    const float* fmap = (const float*)d_in[0];
    const float* Wqvh = (const float*)d_in[1];
    const float* Wqvv = (const float*)d_in[2];
    const float* Wk   = (const float*)d_in[3];
    const float* Wl   = (const float*)d_in[4];
    const float* Wp   = (const float*)d_in[5];
    float* out = (float*)d_out;
    char* ws = (char*)d_ws;

    // ws layout (exactly 128 MiB). cat aliases Fbf (Fbf dead after k_gemm_all).
    bfu* Fbf   = (bfu*)(ws);                     // [16][4096][256] bf16 NHWC : 33,554,432 B
    bfu* cat   = Fbf;                            // alias (written by attn, after Fbf dead)
    bfu* k_all = (bfu*)(ws + 33554432);          // 33,554,432 B
    bfu* lepe  = (bfu*)(ws + 67108864);          // 33,554,432 B
    bfu* qvh   = (bfu*)(ws + 100663296);         // [16][2048][256] : 16,777,216 B
    bfu* qvv   = (bfu*)(ws + 117440512);         // 16,777,216 B -> 134,217,728

    // bf16 weights live in d_out (dead until proj rewrites it at the end).
    // NOTE: k_proj must NOT read from d_out — it writes d_out.
    bfu* Wkl = (bfu*)d_out;                      // [512][256] : 262,144 B
    bfu* Whr = (bfu*)((char*)d_out + 262144);    // [256][256] : 131,072 B
    bfu* Wvr = (bfu*)((char*)d_out + 393216);    // [256][256] : 131,072 B

    k_prep_f<<<dim3(64, 16), 256, 0, stream>>>(fmap, Fbf);
    k_prep_w<<<dim3(512), 256, 0, stream>>>(Wk, Wl, Wqvh, Wqvv, Wkl, Whr, Wvr);
    k_gemm_all<<<dim3(4096), 512, 0, stream>>>(Wkl, Whr, Wvr, Fbf, k_all, lepe, qvh, qvv);
    k_attn<<<dim3(4096), 256, 0, stream>>>(qvh, qvv, k_all, lepe, cat);
    k_proj<<<dim3(32, 2, 16), 512, 0, stream>>>(Wp, cat, fmap, out);
}

// Round 12
// 251.316 us; speedup vs baseline: 1.1222x; 1.1222x over previous
//
#include <hip/hip_runtime.h>
#include <hip/hip_bf16.h>

#define SCALE 0.1767766952966369f  // (256/8)^-0.5

typedef unsigned short bfu;
typedef unsigned int u32;
typedef __attribute__((ext_vector_type(8))) short bf8v;      // MFMA A/B frag (8 bf16)
typedef __attribute__((ext_vector_type(4))) float f32x4;     // MFMA C/D frag
typedef __attribute__((ext_vector_type(8))) unsigned short u16x8;
typedef __attribute__((ext_vector_type(4))) unsigned int u32x4;

__device__ __forceinline__ bfu f2b(float x) {
    __hip_bfloat16 h = __float2bfloat16(x);
    return *(bfu*)&h;
}
__device__ __forceinline__ float bu2f(bfu u) {
    return __uint_as_float(((unsigned int)u) << 16);
}
__device__ __forceinline__ u32 cvtpk(float lo, float hi) {
    u32 r;
    asm("v_cvt_pk_bf16_f32 %0, %1, %2" : "=v"(r) : "v"(lo), "v"(hi));
    return r;
}
__device__ __forceinline__ void gload16(const bfu* g, bfu* l) {
    __builtin_amdgcn_global_load_lds(
        (const __attribute__((address_space(1))) unsigned int*)g,
        (__attribute__((address_space(3))) unsigned int*)l, 16, 0, 0);
}

// ---------------- prep: fmap fp32 NCHW -> bf16 NHWC ----------------
__global__ __launch_bounds__(256) void k_prep_f(const float* __restrict__ fmap,
                                                bfu* __restrict__ Fbf) {
    const int x = blockIdx.x, b = blockIdx.y;
    const int t = threadIdx.x;
    __shared__ float tile[64][69];
    for (int cc = 0; cc < 256; cc += 64) {
        #pragma unroll
        for (int i = 0; i < 4; ++i) {
            const int c = (t >> 4) + i * 16, y4 = (t & 15) * 4;
            const float4 v = *(const float4*)(fmap + (((size_t)b * 256 + cc + c) * 64 + x) * 64 + y4);
            tile[y4][c] = v.x; tile[y4 + 1][c] = v.y; tile[y4 + 2][c] = v.z; tile[y4 + 3][c] = v.w;
        }
        __syncthreads();
        const int y = t >> 2, cs = (t & 3) * 16;
        u16x8 o0, o1;
        #pragma unroll
        for (int j = 0; j < 8; ++j) { o0[j] = f2b(tile[y][cs + j]); o1[j] = f2b(tile[y][cs + 8 + j]); }
        bfu* dst = Fbf + (((size_t)b * 64 + x) * 64 + y) * 256 + cc + cs;
        *(u16x8*)dst = o0; *(u16x8*)(dst + 8) = o1;
        __syncthreads();
    }
}

// ---------------- prep: weights -> bf16 (Wkl stacked; qv reordered r'=kh*128+c) ----------------
__global__ __launch_bounds__(256) void k_prep_w(
    const float* __restrict__ Wk, const float* __restrict__ Wl,
    const float* __restrict__ Wh, const float* __restrict__ Wv,
    bfu* __restrict__ Wkl, bfu* __restrict__ Whr, bfu* __restrict__ Wvr) {
    const int i = blockIdx.x * 256 + threadIdx.x;   // 0..131071
    {
        const int o = i >> 8;
        Wkl[i] = f2b((o < 256) ? Wk[i] : Wl[i - 65536]);
    }
    if (i < 65536) {
        const int o = i >> 8, r = i & 255, kh = r >> 7, c = r & 127;
        const int s = (o * 128 + c) * 2 + kh;
        Whr[i] = f2b(Wh[s]);
        Wvr[i] = f2b(Wv[s]);
    }
}

// ---------------- MFMA GEMM, 128x128 tile, K=256, 8 waves (512 thr) ----------------
// (round-10 config, best measured). B staged via global_load_lds(16B) into
// linear [128][256] LDS, XOR chunk-swizzle on source + read (m104-safe).
template<int MODE>
__global__ __launch_bounds__(512) void k_gemm(
    const bfu* __restrict__ Ab16, const float* __restrict__ Af32,
    const bfu* __restrict__ Bsrc,
    bfu* __restrict__ o_kall, bfu* __restrict__ o_lepe, bfu* __restrict__ o_qv,
    const float* __restrict__ resid, float* __restrict__ outf) {
    const int nt = blockIdx.x, mt = blockIdx.y, b = blockIdx.z;
    const int n0 = nt * 128, m0 = mt * 128;
    const int t = threadIdx.x, lane = t & 63;
    const int wave = t >> 6;               // 0..7
    const int wm = wave >> 1, wn = wave & 1;   // wm 0..3 (M 32), wn 0..1 (N 64)
    const int lq = lane >> 4, lr = lane & 15;
    __shared__ bfu Bs[128 * 256];               // linear, 64 KB
    const bfu* fb = Bsrc + (size_t)b * 1048576;  // 4096 spatial * 256 ch

    {
        const int lrow = lane >> 5;
        const int c1 = lane & 31;
        #pragma unroll
        for (int i = 0; i < 8; ++i) {
            const int row = wave * 16 + i * 2 + lrow;
            const int cS = c1 ^ (row & 7);      // source chunk (inverse swizzle)
            int so;
            if (MODE == 0 || MODE == 3) {
                so = (n0 + row) * 256 + cS * 8;
            } else if (MODE == 1) {
                const int n = n0 + row;
                const int xo = n >> 6, y = n & 63;
                so = ((2 * xo + (cS >> 4)) * 64 + y) * 256 + (cS & 15) * 8;
            } else {
                const int n = n0 + row;
                const int x = n >> 5, yo = n & 31;
                so = (x * 64 + 2 * yo + (cS >> 4)) * 256 + 128 + (cS & 15) * 8;
            }
            gload16(fb + so, Bs + (wave * 16 + i * 2) * 256);
        }
    }
    __syncthreads();

    f32x4 acc[2][4];
    #pragma unroll
    for (int mi = 0; mi < 2; ++mi)
        #pragma unroll
        for (int ni = 0; ni < 4; ++ni) {
            acc[mi][ni][0] = 0.f; acc[mi][ni][1] = 0.f; acc[mi][ni][2] = 0.f; acc[mi][ni][3] = 0.f;
        }

    #pragma unroll
    for (int k0 = 0; k0 < 8; ++k0) {
        bf8v af[2], bv[4];
        if (MODE == 3) {
            #pragma unroll
            for (int mi = 0; mi < 2; ++mi) {
                const float* ap = Af32 + (size_t)(m0 + wm * 32 + mi * 16 + lr) * 256 + k0 * 32 + lq * 8;
                const float4 u0 = *(const float4*)ap;
                const float4 u1 = *(const float4*)(ap + 4);
                bf8v a;
                a[0] = (short)f2b(u0.x); a[1] = (short)f2b(u0.y);
                a[2] = (short)f2b(u0.z); a[3] = (short)f2b(u0.w);
                a[4] = (short)f2b(u1.x); a[5] = (short)f2b(u1.y);
                a[6] = (short)f2b(u1.z); a[7] = (short)f2b(u1.w);
                af[mi] = a;
            }
        } else {
            #pragma unroll
            for (int mi = 0; mi < 2; ++mi)
                af[mi] = *(const bf8v*)(Ab16 + (size_t)(m0 + wm * 32 + mi * 16 + lr) * 256 + k0 * 32 + lq * 8);
        }
        #pragma unroll
        for (int ni = 0; ni < 4; ++ni) {
            const int row = wn * 64 + ni * 16 + lr;
            const int ck = (k0 * 4 + lq) ^ (row & 7);   // swizzled read chunk
            bv[ni] = *(const bf8v*)(Bs + row * 256 + ck * 8);
        }
        #pragma unroll
        for (int mi = 0; mi < 2; ++mi)
            #pragma unroll
            for (int ni = 0; ni < 4; ++ni)
                acc[mi][ni] = __builtin_amdgcn_mfma_f32_16x16x32_bf16(af[mi], bv[ni], acc[mi][ni], 0, 0, 0);
    }

    if (MODE == 0) {
        bfu* outp = (mt < 2) ? o_kall : o_lepe;
        const int chb = (mt & 1) * 128 + wm * 32;
        #pragma unroll
        for (int mi = 0; mi < 2; ++mi)
            #pragma unroll
            for (int ni = 0; ni < 4; ++ni) {
                const int ch = chb + mi * 16 + lq * 4;
                const int ng = n0 + wn * 64 + ni * 16 + lr;
                ushort4 pk;
                pk.x = f2b(acc[mi][ni][0]); pk.y = f2b(acc[mi][ni][1]);
                pk.z = f2b(acc[mi][ni][2]); pk.w = f2b(acc[mi][ni][3]);
                *(ushort4*)(outp + ((size_t)b * 4096 + ng) * 256 + ch) = pk;
            }
    } else if (MODE == 1 || MODE == 2) {
        #pragma unroll
        for (int mi = 0; mi < 2; ++mi)
            #pragma unroll
            for (int ni = 0; ni < 4; ++ni) {
                const int ch = m0 + wm * 32 + mi * 16 + lq * 4;
                const int ng = n0 + wn * 64 + ni * 16 + lr;
                ushort4 pk;
                pk.x = f2b(acc[mi][ni][0]); pk.y = f2b(acc[mi][ni][1]);
                pk.z = f2b(acc[mi][ni][2]); pk.w = f2b(acc[mi][ni][3]);
                *(ushort4*)(o_qv + ((size_t)b * 2048 + ng) * 256 + ch) = pk;
            }
    } else {
        #pragma unroll
        for (int mi = 0; mi < 2; ++mi)
            #pragma unroll
            for (int ni = 0; ni < 4; ++ni) {
                const int ng = n0 + wn * 64 + ni * 16 + lr;
                #pragma unroll
                for (int r = 0; r < 4; ++r) {
                    const int m = m0 + wm * 32 + mi * 16 + lq * 4 + r;
                    const size_t ad = ((size_t)b * 256 + m) * 4096 + ng;
                    outf[ad] = resid[ad] + acc[mi][ni][r];
                }
            }
    }
}

// ---------------- MFMA attention (both branches) ----------------
// h in HIGH bits of blockIdx (heads of a window share bid%8 -> same XCD L2).
// Q and V staged ONCE per block into LDS via gload16 (all 4 waves previously
// re-loaded the same Q vectorized and V as 32 scalar 2B global loads/wave —
// the FETCH excess and the longest latency chain). Q frags: ds_read_b128;
// V frags: 8x ds_read_u16 (LDS latency ~6cyc vs ~300cyc L2).
// No max-subtraction in softmax (|S*SCALE| <~ 1; softmax shift-invariant).
template<int BR>
__global__ __launch_bounds__(256) void k_attn(
    const bfu* __restrict__ Qv, const bfu* __restrict__ Kb,
    const bfu* __restrict__ Lp, bfu* __restrict__ cat) {
    const int bid = blockIdx.x;
    const int h = (bid >> 8) & 7;
    const int bg = bid & 255;
    const int b = bg >> 4, g = bg & 15;
    const int t = threadIdx.x, lane = t & 63, w = t >> 6;
    const int lr = lane & 15, lq = lane >> 4;
    const int chQ = h * 16, chV = 128 + h * 16;
    const int chO = (BR == 0) ? h * 16 : 128 + h * 16;
    const bfu* Qb = Qv + (size_t)b * 2048 * 256;
    const bfu* Kg = Kb + (size_t)b * 4096 * 256 + chO;
    const bfu* Lg = Lp + (size_t)b * 4096 * 256 + chO;
    bfu* Cg = cat + (size_t)b * 4096 * 256 + chO;

    __shared__ __align__(16) bfu q_lds[128 * 16];  // [tok][16ch] 4 KB
    __shared__ __align__(16) bfu v_lds[128 * 16];  // [tok][16ch] 4 KB
    __shared__ float psum[2][256];                 // [gq][wave*64 + q]

    // ---- stage Q,V: thread t covers token t>>1, channel-half t&1.
    // dest byte = wave*1024 + lane*16 == tok*32 + half*16  (exact match)
    {
        const int tok = (w << 5) + (lane >> 1), half = lane & 1;
        const int sp = (BR == 0) ? ((tok >> 2) * 64 + g * 4 + (tok & 3))
                                 : ((g * 4 + (tok >> 5)) * 32 + (tok & 31));
        gload16(Qb + (size_t)sp * 256 + chQ + half * 8, q_lds + w * 512);
        gload16(Qb + (size_t)sp * 256 + chV + half * 8, v_lds + w * 512);
    }

    // K B-frags: col k = 16*(4w+ct)+lr, contraction d = lq*8+j (d>=16 -> 0)
    bf8v kf[4];
    #pragma unroll
    for (int ct = 0; ct < 4; ++ct) {
        const int ktok = (4 * w + ct) * 16 + lr;
        const int sp = (BR == 0) ? ((ktok >> 2) * 64 + g * 4 + (ktok & 3))
                                 : ((g * 4 + (ktok >> 6)) * 64 + (ktok & 63));
        if (lq < 2) kf[ct] = *(const bf8v*)(Kg + (size_t)sp * 256 + lq * 8);
        else        kf[ct] = bf8v{0, 0, 0, 0, 0, 0, 0, 0};
    }
    __syncthreads();   // gload16 drain (vmcnt) + LDS visibility

    f32x4 oacc[4];
    #pragma unroll
    for (int ct = 0; ct < 4; ++ct) { oacc[ct][0] = 0.f; oacc[ct][1] = 0.f; oacc[ct][2] = 0.f; oacc[ct][3] = 0.f; }

    for (int gq = 0; gq < 2; ++gq) {
        // Q A-frags from LDS: row q = gq*64 + qt*16 + lr, contraction d = lq*8+j
        bf8v qf[4];
        #pragma unroll
        for (int qt = 0; qt < 4; ++qt) {
            const int qtok = gq * 64 + qt * 16 + lr;
            if (lq < 2) qf[qt] = *(const bf8v*)(q_lds + qtok * 16 + lq * 8);
            else        qf[qt] = bf8v{0, 0, 0, 0, 0, 0, 0, 0};
        }
        // V^T A-frags from LDS: row d = lr, contraction q = gq*64 + c*32 + lq*8 + j
        bf8v vf[2];
        #pragma unroll
        for (int c = 0; c < 2; ++c)
            #pragma unroll
            for (int j = 0; j < 8; ++j)
                vf[c][j] = (short)v_lds[(gq * 64 + c * 32 + lq * 8 + j) * 16 + lr];

        // Stage 1: S tiles
        f32x4 acc[4][4];
        #pragma unroll
        for (int qt = 0; qt < 4; ++qt)
            #pragma unroll
            for (int ct = 0; ct < 4; ++ct) {
                acc[qt][ct][0] = 0.f; acc[qt][ct][1] = 0.f; acc[qt][ct][2] = 0.f; acc[qt][ct][3] = 0.f;
            }
        #pragma unroll
        for (int qt = 0; qt < 4; ++qt)
            #pragma unroll
            for (int ct = 0; ct < 4; ++ct)
                acc[qt][ct] = __builtin_amdgcn_mfma_f32_16x16x32_bf16(qf[qt], kf[ct], acc[qt][ct], 0, 0, 0);

        // exp (no max subtraction) + sum over k
        #pragma unroll
        for (int qt = 0; qt < 4; ++qt)
            #pragma unroll
            for (int ct = 0; ct < 4; ++ct)
                #pragma unroll
                for (int r = 0; r < 4; ++r)
                    acc[qt][ct][r] = __expf(acc[qt][ct][r] * SCALE);

        float rr[4][4];
        #pragma unroll
        for (int qt = 0; qt < 4; ++qt)
            #pragma unroll
            for (int r = 0; r < 4; ++r)
                rr[qt][r] = (acc[qt][0][r] + acc[qt][1][r]) + (acc[qt][2][r] + acc[qt][3][r]);
        #pragma unroll
        for (int s = 1; s <= 8; s <<= 1)
            #pragma unroll
            for (int qt = 0; qt < 4; ++qt)
                #pragma unroll
                for (int r = 0; r < 4; ++r)
                    rr[qt][r] += __shfl_xor(rr[qt][r], s);
        if (lr == 0) {
            #pragma unroll
            for (int qt = 0; qt < 4; ++qt)
                #pragma unroll
                for (int r = 0; r < 4; ++r)
                    psum[gq][w * 64 + qt * 16 + lq * 4 + r] = rr[qt][r];
        }
        __syncthreads();
        float inv[4][4];
        #pragma unroll
        for (int qt = 0; qt < 4; ++qt)
            #pragma unroll
            for (int r = 0; r < 4; ++r) {
                const int qi = qt * 16 + lq * 4 + r;
                inv[qt][r] = 1.0f / ((psum[gq][qi] + psum[gq][64 + qi]) +
                                     (psum[gq][128 + qi] + psum[gq][192 + qi]));
            }

        // normalize + pack to bf16 pairs (rows r0r1, r2r3)
        u32 pk[4][4][2];
        #pragma unroll
        for (int qt = 0; qt < 4; ++qt)
            #pragma unroll
            for (int ct = 0; ct < 4; ++ct) {
                pk[qt][ct][0] = cvtpk(acc[qt][ct][0] * inv[qt][0], acc[qt][ct][1] * inv[qt][1]);
                pk[qt][ct][1] = cvtpk(acc[qt][ct][2] * inv[qt][2], acc[qt][ct][3] * inv[qt][3]);
            }

        // relayout P into B-frags (8-row granule) and stage-2 MFMA
        const int base = ((lane >> 4) & 1) * 32 + (lane & 15);
        const bool hi = (lq >= 2);
        #pragma unroll
        for (int c = 0; c < 2; ++c) {
            #pragma unroll
            for (int ct = 0; ct < 4; ++ct) {
                const u32 a0 = (u32)__shfl((int)pk[2 * c][ct][0], base);
                const u32 a1 = (u32)__shfl((int)pk[2 * c][ct][1], base);
                const u32 a2 = (u32)__shfl((int)pk[2 * c][ct][0], base + 16);
                const u32 a3 = (u32)__shfl((int)pk[2 * c][ct][1], base + 16);
                const u32 b0 = (u32)__shfl((int)pk[2 * c + 1][ct][0], base);
                const u32 b1 = (u32)__shfl((int)pk[2 * c + 1][ct][1], base);
                const u32 b2 = (u32)__shfl((int)pk[2 * c + 1][ct][0], base + 16);
                const u32 b3 = (u32)__shfl((int)pk[2 * c + 1][ct][1], base + 16);
                u32x4 wd;
                wd[0] = hi ? b0 : a0; wd[1] = hi ? b1 : a1;
                wd[2] = hi ? b2 : a2; wd[3] = hi ? b3 : a3;
                const bf8v pf = __builtin_bit_cast(bf8v, wd);
                oacc[ct] = __builtin_amdgcn_mfma_f32_16x16x32_bf16(vf[c], pf, oacc[ct], 0, 0, 0);
            }
        }
    }

    // epilogue: out^T[d][k]: d = lq*4+r, k = 16*(4w+ct)+lr; add lepe, store bf16
    #pragma unroll
    for (int ct = 0; ct < 4; ++ct) {
        const int ktok = (4 * w + ct) * 16 + lr;
        const int sp = (BR == 0) ? ((ktok >> 2) * 64 + g * 4 + (ktok & 3))
                                 : ((g * 4 + (ktok >> 6)) * 64 + (ktok & 63));
        const size_t off = (size_t)sp * 256 + lq * 4;
        const ushort4 l4 = *(const ushort4*)(Lg + off);
        ushort4 o;
        o.x = f2b(oacc[ct][0] + bu2f(l4.x));
        o.y = f2b(oacc[ct][1] + bu2f(l4.y));
        o.z = f2b(oacc[ct][2] + bu2f(l4.z));
        o.w = f2b(oacc[ct][3] + bu2f(l4.w));
        *(ushort4*)(Cg + off) = o;
    }
}

extern "C" void kernel_launch(void* const* d_in, const int* in_sizes, int n_in,
                              void* d_out, int out_size, void* d_ws, size_t ws_size,
                              hipStream_t stream) {
    const float* fmap = (const float*)d_in[0];
    const float* Wqvh = (const float*)d_in[1];
    const float* Wqvv = (const float*)d_in[2];
    const float* Wk   = (const float*)d_in[3];
    const float* Wl   = (const float*)d_in[4];
    const float* Wp   = (const float*)d_in[5];
    float* out = (float*)d_out;
    char* ws = (char*)d_ws;

    // ws layout (exactly 128 MiB). cat aliases Fbf (Fbf dead after the qv GEMMs).
    bfu* Fbf   = (bfu*)(ws);                     // [16][4096][256] bf16 NHWC : 33,554,432 B
    bfu* cat   = Fbf;                            // alias (written by attn, after Fbf dead)
    bfu* k_all = (bfu*)(ws + 33554432);          // 33,554,432 B
    bfu* lepe  = (bfu*)(ws + 67108864);          // 33,554,432 B
    bfu* qvh   = (bfu*)(ws + 100663296);         // [16][2048][256] : 16,777,216 B
    bfu* qvv   = (bfu*)(ws + 117440512);         // 16,777,216 B -> 134,217,728

    // bf16 weights live in d_out (dead until proj rewrites it at the end).
    // NOTE: proj (k_gemm<3>) must NOT read from d_out — it writes d_out.
    bfu* Wkl = (bfu*)d_out;                      // [512][256] : 262,144 B
    bfu* Whr = (bfu*)((char*)d_out + 262144);    // [256][256] : 131,072 B
    bfu* Wvr = (bfu*)((char*)d_out + 393216);    // [256][256] : 131,072 B

    k_prep_f<<<dim3(64, 16), 256, 0, stream>>>(fmap, Fbf);
    k_prep_w<<<dim3(512), 256, 0, stream>>>(Wk, Wl, Wqvh, Wqvv, Wkl, Whr, Wvr);
    k_gemm<0><<<dim3(32, 4, 16), 512, 0, stream>>>(Wkl, nullptr, Fbf, k_all, lepe, nullptr, nullptr, nullptr);
    k_gemm<1><<<dim3(16, 2, 16), 512, 0, stream>>>(Whr, nullptr, Fbf, nullptr, nullptr, qvh, nullptr, nullptr);
    k_gemm<2><<<dim3(16, 2, 16), 512, 0, stream>>>(Wvr, nullptr, Fbf, nullptr, nullptr, qvv, nullptr, nullptr);
    k_attn<0><<<dim3(2048), 256, 0, stream>>>(qvh, k_all, lepe, cat);
    k_attn<1><<<dim3(2048), 256, 0, stream>>>(qvv, k_all, lepe, cat);
    k_gemm<3><<<dim3(32, 2, 16), 512, 0, stream>>>(nullptr, Wp, cat, nullptr, nullptr, nullptr, fmap, out);
}

// Round 13
// 233.181 us; speedup vs baseline: 1.2095x; 1.0778x over previous
//
#include <hip/hip_runtime.h>
#include <hip/hip_bf16.h>

#define QSC 0.25503533f   // SCALE * log2(e); folded into stored q channels

typedef unsigned short bfu;
typedef unsigned int u32;
typedef __attribute__((ext_vector_type(8))) short bf8v;      // MFMA A/B frag (8 bf16)
typedef __attribute__((ext_vector_type(4))) float f32x4;     // MFMA C/D frag
typedef __attribute__((ext_vector_type(8))) unsigned short u16x8;
typedef __attribute__((ext_vector_type(4))) unsigned int u32x4;

__device__ __forceinline__ bfu f2b(float x) {
    __hip_bfloat16 h = __float2bfloat16(x);
    return *(bfu*)&h;
}
__device__ __forceinline__ float bu2f(bfu u) {
    return __uint_as_float(((unsigned int)u) << 16);
}
__device__ __forceinline__ u32 cvtpk(float lo, float hi) {
    u32 r;
    asm("v_cvt_pk_bf16_f32 %0, %1, %2" : "=v"(r) : "v"(lo), "v"(hi));
    return r;
}
__device__ __forceinline__ void gload16(const bfu* g, bfu* l) {
    __builtin_amdgcn_global_load_lds(
        (const __attribute__((address_space(1))) unsigned int*)g,
        (__attribute__((address_space(3))) unsigned int*)l, 16, 0, 0);
}

// ---------------- prep: fmap fp32 NCHW -> bf16 NHWC ----------------
__global__ __launch_bounds__(256) void k_prep_f(const float* __restrict__ fmap,
                                                bfu* __restrict__ Fbf) {
    const int x = blockIdx.x, b = blockIdx.y;
    const int t = threadIdx.x;
    __shared__ float tile[64][69];
    for (int cc = 0; cc < 256; cc += 64) {
        #pragma unroll
        for (int i = 0; i < 4; ++i) {
            const int c = (t >> 4) + i * 16, y4 = (t & 15) * 4;
            const float4 v = *(const float4*)(fmap + (((size_t)b * 256 + cc + c) * 64 + x) * 64 + y4);
            tile[y4][c] = v.x; tile[y4 + 1][c] = v.y; tile[y4 + 2][c] = v.z; tile[y4 + 3][c] = v.w;
        }
        __syncthreads();
        const int y = t >> 2, cs = (t & 3) * 16;
        u16x8 o0, o1;
        #pragma unroll
        for (int j = 0; j < 8; ++j) { o0[j] = f2b(tile[y][cs + j]); o1[j] = f2b(tile[y][cs + 8 + j]); }
        bfu* dst = Fbf + (((size_t)b * 64 + x) * 64 + y) * 256 + cc + cs;
        *(u16x8*)dst = o0; *(u16x8*)(dst + 8) = o1;
        __syncthreads();
    }
}

// ---------------- prep: weights -> bf16 (Wkl stacked; qv reordered r'=kh*128+c) ----------------
__global__ __launch_bounds__(256) void k_prep_w(
    const float* __restrict__ Wk, const float* __restrict__ Wl,
    const float* __restrict__ Wh, const float* __restrict__ Wv,
    bfu* __restrict__ Wkl, bfu* __restrict__ Whr, bfu* __restrict__ Wvr) {
    const int i = blockIdx.x * 256 + threadIdx.x;   // 0..131071
    {
        const int o = i >> 8;
        Wkl[i] = f2b((o < 256) ? Wk[i] : Wl[i - 65536]);
    }
    if (i < 65536) {
        const int o = i >> 8, r = i & 255, kh = r >> 7, c = r & 127;
        const int s = (o * 128 + c) * 2 + kh;
        Whr[i] = f2b(Wh[s]);
        Wvr[i] = f2b(Wv[s]);
    }
}

// ---------------- MFMA GEMM, 2-phase pipelined, 512 threads ----------------
// Each block: 4 consecutive N=64 tiles, double-buffered 2x32KB LDS.
// Loop: stage(t+1 into alt buf) -> compute(t) -> barrier (vmcnt drain hidden
// under compute). A-fragments hoisted into registers once per block (af[8][2],
// reused across all 4 tiles). B staged via global_load_lds(16B) with XOR
// chunk-swizzle c'=c^(row&7) on the per-lane GLOBAL source address and the
// same XOR on the ds_read_b128 address (dest stays linear: m104).
// MODE 0: k_all+lepe (M=512 stacked Wkl)  -> bf16 NHWC
// MODE 1: qv_h (Whr); mt==0 (q chans) scaled by QSC -> bf16 NHWC
// MODE 2: qv_v (Wvr); mt==0 scaled                 -> bf16 NHWC
// MODE 3: proj (W_proj fp32 from d_in, cvt once; +resid) -> fp32 NCHW
template<int MODE>
__global__ __launch_bounds__(512) void k_gemm(
    const bfu* __restrict__ Ab16, const float* __restrict__ Af32,
    const bfu* __restrict__ Bsrc,
    bfu* __restrict__ o_kall, bfu* __restrict__ o_lepe, bfu* __restrict__ o_qv,
    const float* __restrict__ resid, float* __restrict__ outf) {
    const int ng = blockIdx.x, mt = blockIdx.y, b = blockIdx.z;
    const int m0 = mt * 128;
    const int t = threadIdx.x, lane = t & 63;
    const int wave = t >> 6;                   // 0..7
    const int wm = wave >> 1, wn = wave & 1;   // wm 0..3 (M 32), wn 0..1 (N 32)
    const int lq = lane >> 4, lr = lane & 15;
    __shared__ bfu Bs[2][64 * 256];            // 2 x 32 KB
    const bfu* fb = Bsrc + (size_t)b * 1048576;

    // ---- hoist A into registers (reused by all 4 tiles)
    bf8v af[8][2];
    if (MODE == 3) {
        #pragma unroll
        for (int k0 = 0; k0 < 8; ++k0)
            #pragma unroll
            for (int mi = 0; mi < 2; ++mi) {
                const float* ap = Af32 + (size_t)(m0 + wm * 32 + mi * 16 + lr) * 256 + k0 * 32 + lq * 8;
                const float4 u0 = *(const float4*)ap;
                const float4 u1 = *(const float4*)(ap + 4);
                bf8v a;
                a[0] = (short)f2b(u0.x); a[1] = (short)f2b(u0.y);
                a[2] = (short)f2b(u0.z); a[3] = (short)f2b(u0.w);
                a[4] = (short)f2b(u1.x); a[5] = (short)f2b(u1.y);
                a[6] = (short)f2b(u1.z); a[7] = (short)f2b(u1.w);
                af[k0][mi] = a;
            }
    } else {
        #pragma unroll
        for (int k0 = 0; k0 < 8; ++k0)
            #pragma unroll
            for (int mi = 0; mi < 2; ++mi)
                af[k0][mi] = *(const bf8v*)(Ab16 + (size_t)(m0 + wm * 32 + mi * 16 + lr) * 256 + k0 * 32 + lq * 8);
    }

    // ---- stage one N=64 tile into buf (4 gload16/wave; 2 rows per gload16)
    auto stage = [&](int buf, int nt) {
        const int n0 = nt * 64;
        const int lrow = lane >> 5, c1 = lane & 31;
        #pragma unroll
        for (int i = 0; i < 4; ++i) {
            const int row = wave * 8 + i * 2 + lrow;
            const int cS = c1 ^ (row & 7);     // source chunk (inverse swizzle)
            int so;
            if (MODE == 0 || MODE == 3) {
                so = (n0 + row) * 256 + cS * 8;
            } else if (MODE == 1) {
                const int n = n0 + row;
                const int xo = n >> 6, y = n & 63;
                so = ((2 * xo + (cS >> 4)) * 64 + y) * 256 + (cS & 15) * 8;
            } else {
                const int n = n0 + row;
                const int x = n >> 5, yo = n & 31;
                so = (x * 64 + 2 * yo + (cS >> 4)) * 256 + 128 + (cS & 15) * 8;
            }
            gload16(fb + so, &Bs[buf][(wave * 8 + i * 2) * 256]);
        }
    };

    const int nt0 = ng * 4;
    stage(0, nt0);
    __syncthreads();

    for (int tt = 0; tt < 4; ++tt) {
        if (tt + 1 < 4) stage((tt + 1) & 1, nt0 + tt + 1);   // prefetch next

        const int buf = tt & 1;
        f32x4 acc[2][2];
        #pragma unroll
        for (int mi = 0; mi < 2; ++mi)
            #pragma unroll
            for (int ni = 0; ni < 2; ++ni) {
                acc[mi][ni][0] = 0.f; acc[mi][ni][1] = 0.f;
                acc[mi][ni][2] = 0.f; acc[mi][ni][3] = 0.f;
            }
        #pragma unroll
        for (int k0 = 0; k0 < 8; ++k0) {
            bf8v bv[2];
            #pragma unroll
            for (int ni = 0; ni < 2; ++ni) {
                const int row = wn * 32 + ni * 16 + lr;
                const int ck = (k0 * 4 + lq) ^ (row & 7);
                bv[ni] = *(const bf8v*)(&Bs[buf][row * 256 + ck * 8]);
            }
            #pragma unroll
            for (int mi = 0; mi < 2; ++mi)
                #pragma unroll
                for (int ni = 0; ni < 2; ++ni)
                    acc[mi][ni] = __builtin_amdgcn_mfma_f32_16x16x32_bf16(af[k0][mi], bv[ni], acc[mi][ni], 0, 0, 0);
        }

        const int n0 = (nt0 + tt) * 64;
        if (MODE == 0) {
            bfu* outp = (mt < 2) ? o_kall : o_lepe;
            const int chb = (mt & 1) * 128 + wm * 32;
            #pragma unroll
            for (int mi = 0; mi < 2; ++mi)
                #pragma unroll
                for (int ni = 0; ni < 2; ++ni) {
                    const int ch = chb + mi * 16 + lq * 4;
                    const int ngl = n0 + wn * 32 + ni * 16 + lr;
                    ushort4 pk;
                    pk.x = f2b(acc[mi][ni][0]); pk.y = f2b(acc[mi][ni][1]);
                    pk.z = f2b(acc[mi][ni][2]); pk.w = f2b(acc[mi][ni][3]);
                    *(ushort4*)(outp + ((size_t)b * 4096 + ngl) * 256 + ch) = pk;
                }
        } else if (MODE == 1 || MODE == 2) {
            const float qs = (mt == 0) ? QSC : 1.0f;   // pre-scale q channels
            #pragma unroll
            for (int mi = 0; mi < 2; ++mi)
                #pragma unroll
                for (int ni = 0; ni < 2; ++ni) {
                    const int ch = m0 + wm * 32 + mi * 16 + lq * 4;
                    const int ngl = n0 + wn * 32 + ni * 16 + lr;
                    ushort4 pk;
                    pk.x = f2b(acc[mi][ni][0] * qs); pk.y = f2b(acc[mi][ni][1] * qs);
                    pk.z = f2b(acc[mi][ni][2] * qs); pk.w = f2b(acc[mi][ni][3] * qs);
                    *(ushort4*)(o_qv + ((size_t)b * 2048 + ngl) * 256 + ch) = pk;
                }
        } else {
            #pragma unroll
            for (int mi = 0; mi < 2; ++mi)
                #pragma unroll
                for (int ni = 0; ni < 2; ++ni) {
                    const int ngl = n0 + wn * 32 + ni * 16 + lr;
                    #pragma unroll
                    for (int r = 0; r < 4; ++r) {
                        const int m = m0 + wm * 32 + mi * 16 + lq * 4 + r;
                        const size_t ad = ((size_t)b * 256 + m) * 4096 + ngl;
                        outf[ad] = resid[ad] + acc[mi][ni][r];
                    }
                }
        }
        if (tt + 1 < 4) __syncthreads();   // drains prefetch (hidden under compute)
    }
}

// ---------------- MFMA attention (both branches) ----------------
// h in HIGH bits of blockIdx (heads of a window share bid%8 -> same XCD L2).
// Q/V staged once per block via gload16. Q pre-scaled by SCALE*log2e at
// production -> softmax is a bare exp2f. No max-subtraction (|S_hat| small;
// softmax shift-invariant).
template<int BR>
__global__ __launch_bounds__(256) void k_attn(
    const bfu* __restrict__ Qv, const bfu* __restrict__ Kb,
    const bfu* __restrict__ Lp, bfu* __restrict__ cat) {
    const int bid = blockIdx.x;
    const int h = (bid >> 8) & 7;
    const int bg = bid & 255;
    const int b = bg >> 4, g = bg & 15;
    const int t = threadIdx.x, lane = t & 63, w = t >> 6;
    const int lr = lane & 15, lq = lane >> 4;
    const int chQ = h * 16, chV = 128 + h * 16;
    const int chO = (BR == 0) ? h * 16 : 128 + h * 16;
    const bfu* Qb = Qv + (size_t)b * 2048 * 256;
    const bfu* Kg = Kb + (size_t)b * 4096 * 256 + chO;
    const bfu* Lg = Lp + (size_t)b * 4096 * 256 + chO;
    bfu* Cg = cat + (size_t)b * 4096 * 256 + chO;

    __shared__ __align__(16) bfu q_lds[128 * 16];  // [tok][16ch] 4 KB
    __shared__ __align__(16) bfu v_lds[128 * 16];  // [tok][16ch] 4 KB
    __shared__ float psum[2][256];                 // [gq][wave*64 + q]

    {
        const int tok = (w << 5) + (lane >> 1), half = lane & 1;
        const int sp = (BR == 0) ? ((tok >> 2) * 64 + g * 4 + (tok & 3))
                                 : ((g * 4 + (tok >> 5)) * 32 + (tok & 31));
        gload16(Qb + (size_t)sp * 256 + chQ + half * 8, q_lds + w * 512);
        gload16(Qb + (size_t)sp * 256 + chV + half * 8, v_lds + w * 512);
    }

    bf8v kf[4];
    #pragma unroll
    for (int ct = 0; ct < 4; ++ct) {
        const int ktok = (4 * w + ct) * 16 + lr;
        const int sp = (BR == 0) ? ((ktok >> 2) * 64 + g * 4 + (ktok & 3))
                                 : ((g * 4 + (ktok >> 6)) * 64 + (ktok & 63));
        if (lq < 2) kf[ct] = *(const bf8v*)(Kg + (size_t)sp * 256 + lq * 8);
        else        kf[ct] = bf8v{0, 0, 0, 0, 0, 0, 0, 0};
    }
    __syncthreads();   // gload16 drain + LDS visibility

    f32x4 oacc[4];
    #pragma unroll
    for (int ct = 0; ct < 4; ++ct) { oacc[ct][0] = 0.f; oacc[ct][1] = 0.f; oacc[ct][2] = 0.f; oacc[ct][3] = 0.f; }

    for (int gq = 0; gq < 2; ++gq) {
        bf8v qf[4];
        #pragma unroll
        for (int qt = 0; qt < 4; ++qt) {
            const int qtok = gq * 64 + qt * 16 + lr;
            if (lq < 2) qf[qt] = *(const bf8v*)(q_lds + qtok * 16 + lq * 8);
            else        qf[qt] = bf8v{0, 0, 0, 0, 0, 0, 0, 0};
        }
        bf8v vf[2];
        #pragma unroll
        for (int c = 0; c < 2; ++c)
            #pragma unroll
            for (int j = 0; j < 8; ++j)
                vf[c][j] = (short)v_lds[(gq * 64 + c * 32 + lq * 8 + j) * 16 + lr];

        f32x4 acc[4][4];
        #pragma unroll
        for (int qt = 0; qt < 4; ++qt)
            #pragma unroll
            for (int ct = 0; ct < 4; ++ct) {
                acc[qt][ct][0] = 0.f; acc[qt][ct][1] = 0.f; acc[qt][ct][2] = 0.f; acc[qt][ct][3] = 0.f;
            }
        #pragma unroll
        for (int qt = 0; qt < 4; ++qt)
            #pragma unroll
            for (int ct = 0; ct < 4; ++ct)
                acc[qt][ct] = __builtin_amdgcn_mfma_f32_16x16x32_bf16(qf[qt], kf[ct], acc[qt][ct], 0, 0, 0);

        // P = exp2(S_hat)  (SCALE*log2e pre-folded into q)
        #pragma unroll
        for (int qt = 0; qt < 4; ++qt)
            #pragma unroll
            for (int ct = 0; ct < 4; ++ct)
                #pragma unroll
                for (int r = 0; r < 4; ++r)
                    acc[qt][ct][r] = exp2f(acc[qt][ct][r]);

        float rr[4][4];
        #pragma unroll
        for (int qt = 0; qt < 4; ++qt)
            #pragma unroll
            for (int r = 0; r < 4; ++r)
                rr[qt][r] = (acc[qt][0][r] + acc[qt][1][r]) + (acc[qt][2][r] + acc[qt][3][r]);
        #pragma unroll
        for (int s = 1; s <= 8; s <<= 1)
            #pragma unroll
            for (int qt = 0; qt < 4; ++qt)
                #pragma unroll
                for (int r = 0; r < 4; ++r)
                    rr[qt][r] += __shfl_xor(rr[qt][r], s);
        if (lr == 0) {
            #pragma unroll
            for (int qt = 0; qt < 4; ++qt)
                #pragma unroll
                for (int r = 0; r < 4; ++r)
                    psum[gq][w * 64 + qt * 16 + lq * 4 + r] = rr[qt][r];
        }
        __syncthreads();
        float inv[4][4];
        #pragma unroll
        for (int qt = 0; qt < 4; ++qt)
            #pragma unroll
            for (int r = 0; r < 4; ++r) {
                const int qi = qt * 16 + lq * 4 + r;
                inv[qt][r] = 1.0f / ((psum[gq][qi] + psum[gq][64 + qi]) +
                                     (psum[gq][128 + qi] + psum[gq][192 + qi]));
            }

        u32 pk[4][4][2];
        #pragma unroll
        for (int qt = 0; qt < 4; ++qt)
            #pragma unroll
            for (int ct = 0; ct < 4; ++ct) {
                pk[qt][ct][0] = cvtpk(acc[qt][ct][0] * inv[qt][0], acc[qt][ct][1] * inv[qt][1]);
                pk[qt][ct][1] = cvtpk(acc[qt][ct][2] * inv[qt][2], acc[qt][ct][3] * inv[qt][3]);
            }

        const int base = ((lane >> 4) & 1) * 32 + (lane & 15);
        const bool hi = (lq >= 2);
        #pragma unroll
        for (int c = 0; c < 2; ++c) {
            #pragma unroll
            for (int ct = 0; ct < 4; ++ct) {
                const u32 a0 = (u32)__shfl((int)pk[2 * c][ct][0], base);
                const u32 a1 = (u32)__shfl((int)pk[2 * c][ct][1], base);
                const u32 a2 = (u32)__shfl((int)pk[2 * c][ct][0], base + 16);
                const u32 a3 = (u32)__shfl((int)pk[2 * c][ct][1], base + 16);
                const u32 b0 = (u32)__shfl((int)pk[2 * c + 1][ct][0], base);
                const u32 b1 = (u32)__shfl((int)pk[2 * c + 1][ct][1], base);
                const u32 b2 = (u32)__shfl((int)pk[2 * c + 1][ct][0], base + 16);
                const u32 b3 = (u32)__shfl((int)pk[2 * c + 1][ct][1], base + 16);
                u32x4 wd;
                wd[0] = hi ? b0 : a0; wd[1] = hi ? b1 : a1;
                wd[2] = hi ? b2 : a2; wd[3] = hi ? b3 : a3;
                const bf8v pf = __builtin_bit_cast(bf8v, wd);
                oacc[ct] = __builtin_amdgcn_mfma_f32_16x16x32_bf16(vf[c], pf, oacc[ct], 0, 0, 0);
            }
        }
    }

    #pragma unroll
    for (int ct = 0; ct < 4; ++ct) {
        const int ktok = (4 * w + ct) * 16 + lr;
        const int sp = (BR == 0) ? ((ktok >> 2) * 64 + g * 4 + (ktok & 3))
                                 : ((g * 4 + (ktok >> 6)) * 64 + (ktok & 63));
        const size_t off = (size_t)sp * 256 + lq * 4;
        const ushort4 l4 = *(const ushort4*)(Lg + off);
        ushort4 o;
        o.x = f2b(oacc[ct][0] + bu2f(l4.x));
        o.y = f2b(oacc[ct][1] + bu2f(l4.y));
        o.z = f2b(oacc[ct][2] + bu2f(l4.z));
        o.w = f2b(oacc[ct][3] + bu2f(l4.w));
        *(ushort4*)(Cg + off) = o;
    }
}

extern "C" void kernel_launch(void* const* d_in, const int* in_sizes, int n_in,
                              void* d_out, int out_size, void* d_ws, size_t ws_size,
                              hipStream_t stream) {
    const float* fmap = (const float*)d_in[0];
    const float* Wqvh = (const float*)d_in[1];
    const float* Wqvv = (const float*)d_in[2];
    const float* Wk   = (const float*)d_in[3];
    const float* Wl   = (const float*)d_in[4];
    const float* Wp   = (const float*)d_in[5];
    float* out = (float*)d_out;
    char* ws = (char*)d_ws;

    // ws layout (exactly 128 MiB). cat aliases Fbf (Fbf dead after the qv GEMMs).
    bfu* Fbf   = (bfu*)(ws);                     // [16][4096][256] bf16 NHWC : 33,554,432 B
    bfu* cat   = Fbf;                            // alias (written by attn, after Fbf dead)
    bfu* k_all = (bfu*)(ws + 33554432);          // 33,554,432 B
    bfu* lepe  = (bfu*)(ws + 67108864);          // 33,554,432 B
    bfu* qvh   = (bfu*)(ws + 100663296);         // [16][2048][256] : 16,777,216 B
    bfu* qvv   = (bfu*)(ws + 117440512);         // 16,777,216 B -> 134,217,728

    // bf16 weights live in d_out (dead until proj rewrites it at the end).
    // NOTE: proj (k_gemm<3>) must NOT read from d_out — it writes d_out.
    bfu* Wkl = (bfu*)d_out;                      // [512][256] : 262,144 B
    bfu* Whr = (bfu*)((char*)d_out + 262144);    // [256][256] : 131,072 B
    bfu* Wvr = (bfu*)((char*)d_out + 393216);    // [256][256] : 131,072 B

    k_prep_f<<<dim3(64, 16), 256, 0, stream>>>(fmap, Fbf);
    k_prep_w<<<dim3(512), 256, 0, stream>>>(Wk, Wl, Wqvh, Wqvv, Wkl, Whr, Wvr);
    k_gemm<0><<<dim3(16, 4, 16), 512, 0, stream>>>(Wkl, nullptr, Fbf, k_all, lepe, nullptr, nullptr, nullptr);
    k_gemm<1><<<dim3(8, 2, 16), 512, 0, stream>>>(Whr, nullptr, Fbf, nullptr, nullptr, qvh, nullptr, nullptr);
    k_gemm<2><<<dim3(8, 2, 16), 512, 0, stream>>>(Wvr, nullptr, Fbf, nullptr, nullptr, qvv, nullptr, nullptr);
    k_attn<0><<<dim3(2048), 256, 0, stream>>>(qvh, k_all, lepe, cat);
    k_attn<1><<<dim3(2048), 256, 0, stream>>>(qvv, k_all, lepe, cat);
    k_gemm<3><<<dim3(16, 2, 16), 512, 0, stream>>>(nullptr, Wp, cat, nullptr, nullptr, nullptr, fmap, out);
}

// Round 16
// 216.705 us; speedup vs baseline: 1.3015x; 1.0760x over previous
//
#include <hip/hip_runtime.h>
#include <hip/hip_bf16.h>

#define QSC 0.25503533f   // SCALE * log2(e); folded into stored q channels

typedef unsigned short bfu;
typedef unsigned int u32;
typedef __attribute__((ext_vector_type(8))) short bf8v;      // MFMA A/B frag (8 bf16, K=32)
typedef __attribute__((ext_vector_type(4))) float f32x4;     // MFMA C/D frag
typedef __attribute__((ext_vector_type(8))) unsigned short u16x8;
typedef __attribute__((ext_vector_type(4))) unsigned int u32x4;

__device__ __forceinline__ bfu f2b(float x) {
    __hip_bfloat16 h = __float2bfloat16(x);
    return *(bfu*)&h;
}
__device__ __forceinline__ float bu2f(bfu u) {
    return __uint_as_float(((unsigned int)u) << 16);
}
__device__ __forceinline__ u32 cvtpk(float lo, float hi) {
    u32 r;
    asm("v_cvt_pk_bf16_f32 %0, %1, %2" : "=v"(r) : "v"(lo), "v"(hi));
    return r;
}
__device__ __forceinline__ void gload16(const bfu* g, bfu* l) {
    __builtin_amdgcn_global_load_lds(
        (const __attribute__((address_space(1))) unsigned int*)g,
        (__attribute__((address_space(3))) unsigned int*)l, 16, 0, 0);
}

// ---------------- prep: fmap fp32 NCHW -> bf16 NHWC ----------------
__global__ __launch_bounds__(256) void k_prep_f(const float* __restrict__ fmap,
                                                bfu* __restrict__ Fbf) {
    const int x = blockIdx.x, b = blockIdx.y;
    const int t = threadIdx.x;
    __shared__ float tile[64][69];
    for (int cc = 0; cc < 256; cc += 64) {
        #pragma unroll
        for (int i = 0; i < 4; ++i) {
            const int c = (t >> 4) + i * 16, y4 = (t & 15) * 4;
            const float4 v = *(const float4*)(fmap + (((size_t)b * 256 + cc + c) * 64 + x) * 64 + y4);
            tile[y4][c] = v.x; tile[y4 + 1][c] = v.y; tile[y4 + 2][c] = v.z; tile[y4 + 3][c] = v.w;
        }
        __syncthreads();
        const int y = t >> 2, cs = (t & 3) * 16;
        u16x8 o0, o1;
        #pragma unroll
        for (int j = 0; j < 8; ++j) { o0[j] = f2b(tile[y][cs + j]); o1[j] = f2b(tile[y][cs + 8 + j]); }
        bfu* dst = Fbf + (((size_t)b * 64 + x) * 64 + y) * 256 + cc + cs;
        *(u16x8*)dst = o0; *(u16x8*)(dst + 8) = o1;
        __syncthreads();
    }
}

// ---------------- prep: weights -> bf16 (Wkl stacked; qv reordered r'=kh*128+c) ----------------
__global__ __launch_bounds__(256) void k_prep_w(
    const float* __restrict__ Wk, const float* __restrict__ Wl,
    const float* __restrict__ Wh, const float* __restrict__ Wv,
    bfu* __restrict__ Wkl, bfu* __restrict__ Whr, bfu* __restrict__ Wvr) {
    const int i = blockIdx.x * 256 + threadIdx.x;   // 0..131071
    {
        const int o = i >> 8;
        Wkl[i] = f2b((o < 256) ? Wk[i] : Wl[i - 65536]);
    }
    if (i < 65536) {
        const int o = i >> 8, r = i & 255, kh = r >> 7, c = r & 127;
        const int s = (o * 128 + c) * 2 + kh;
        Whr[i] = f2b(Wh[s]);
        Wvr[i] = f2b(Wv[s]);
    }
}

// ---------------- MFMA GEMM, 2-phase pipelined, 512 threads (round-13) ----------------
template<int MODE>
__global__ __launch_bounds__(512) void k_gemm(
    const bfu* __restrict__ Ab16, const float* __restrict__ Af32,
    const bfu* __restrict__ Bsrc,
    bfu* __restrict__ o_kall, bfu* __restrict__ o_lepe, bfu* __restrict__ o_qv,
    const float* __restrict__ resid, float* __restrict__ outf) {
    const int ng = blockIdx.x, mt = blockIdx.y, b = blockIdx.z;
    const int m0 = mt * 128;
    const int t = threadIdx.x, lane = t & 63;
    const int wave = t >> 6;
    const int wm = wave >> 1, wn = wave & 1;
    const int lq = lane >> 4, lr = lane & 15;
    __shared__ bfu Bs[2][64 * 256];            // 2 x 32 KB
    const bfu* fb = Bsrc + (size_t)b * 1048576;

    bf8v af[8][2];
    if (MODE == 3) {
        #pragma unroll
        for (int k0 = 0; k0 < 8; ++k0)
            #pragma unroll
            for (int mi = 0; mi < 2; ++mi) {
                const float* ap = Af32 + (size_t)(m0 + wm * 32 + mi * 16 + lr) * 256 + k0 * 32 + lq * 8;
                const float4 u0 = *(const float4*)ap;
                const float4 u1 = *(const float4*)(ap + 4);
                bf8v a;
                a[0] = (short)f2b(u0.x); a[1] = (short)f2b(u0.y);
                a[2] = (short)f2b(u0.z); a[3] = (short)f2b(u0.w);
                a[4] = (short)f2b(u1.x); a[5] = (short)f2b(u1.y);
                a[6] = (short)f2b(u1.z); a[7] = (short)f2b(u1.w);
                af[k0][mi] = a;
            }
    } else {
        #pragma unroll
        for (int k0 = 0; k0 < 8; ++k0)
            #pragma unroll
            for (int mi = 0; mi < 2; ++mi)
                af[k0][mi] = *(const bf8v*)(Ab16 + (size_t)(m0 + wm * 32 + mi * 16 + lr) * 256 + k0 * 32 + lq * 8);
    }

    auto stage = [&](int buf, int nt) {
        const int n0 = nt * 64;
        const int lrow = lane >> 5, c1 = lane & 31;
        #pragma unroll
        for (int i = 0; i < 4; ++i) {
            const int row = wave * 8 + i * 2 + lrow;
            const int cS = c1 ^ (row & 7);
            int so;
            if (MODE == 0 || MODE == 3) {
                so = (n0 + row) * 256 + cS * 8;
            } else if (MODE == 1) {
                const int n = n0 + row;
                const int xo = n >> 6, y = n & 63;
                so = ((2 * xo + (cS >> 4)) * 64 + y) * 256 + (cS & 15) * 8;
            } else {
                const int n = n0 + row;
                const int x = n >> 5, yo = n & 31;
                so = (x * 64 + 2 * yo + (cS >> 4)) * 256 + 128 + (cS & 15) * 8;
            }
            gload16(fb + so, &Bs[buf][(wave * 8 + i * 2) * 256]);
        }
    };

    const int nt0 = ng * 4;
    stage(0, nt0);
    __syncthreads();

    for (int tt = 0; tt < 4; ++tt) {
        if (tt + 1 < 4) stage((tt + 1) & 1, nt0 + tt + 1);

        const int buf = tt & 1;
        f32x4 acc[2][2];
        #pragma unroll
        for (int mi = 0; mi < 2; ++mi)
            #pragma unroll
            for (int ni = 0; ni < 2; ++ni) {
                acc[mi][ni][0] = 0.f; acc[mi][ni][1] = 0.f;
                acc[mi][ni][2] = 0.f; acc[mi][ni][3] = 0.f;
            }
        #pragma unroll
        for (int k0 = 0; k0 < 8; ++k0) {
            bf8v bv[2];
            #pragma unroll
            for (int ni = 0; ni < 2; ++ni) {
                const int row = wn * 32 + ni * 16 + lr;
                const int ck = (k0 * 4 + lq) ^ (row & 7);
                bv[ni] = *(const bf8v*)(&Bs[buf][row * 256 + ck * 8]);
            }
            #pragma unroll
            for (int mi = 0; mi < 2; ++mi)
                #pragma unroll
                for (int ni = 0; ni < 2; ++ni)
                    acc[mi][ni] = __builtin_amdgcn_mfma_f32_16x16x32_bf16(af[k0][mi], bv[ni], acc[mi][ni], 0, 0, 0);
        }

        const int n0 = (nt0 + tt) * 64;
        if (MODE == 0) {
            bfu* outp = (mt < 2) ? o_kall : o_lepe;
            const int chb = (mt & 1) * 128 + wm * 32;
            #pragma unroll
            for (int mi = 0; mi < 2; ++mi)
                #pragma unroll
                for (int ni = 0; ni < 2; ++ni) {
                    const int ch = chb + mi * 16 + lq * 4;
                    const int ngl = n0 + wn * 32 + ni * 16 + lr;
                    ushort4 pk;
                    pk.x = f2b(acc[mi][ni][0]); pk.y = f2b(acc[mi][ni][1]);
                    pk.z = f2b(acc[mi][ni][2]); pk.w = f2b(acc[mi][ni][3]);
                    *(ushort4*)(outp + ((size_t)b * 4096 + ngl) * 256 + ch) = pk;
                }
        } else if (MODE == 1 || MODE == 2) {
            const float qs = (mt == 0) ? QSC : 1.0f;
            #pragma unroll
            for (int mi = 0; mi < 2; ++mi)
                #pragma unroll
                for (int ni = 0; ni < 2; ++ni) {
                    const int ch = m0 + wm * 32 + mi * 16 + lq * 4;
                    const int ngl = n0 + wn * 32 + ni * 16 + lr;
                    ushort4 pk;
                    pk.x = f2b(acc[mi][ni][0] * qs); pk.y = f2b(acc[mi][ni][1] * qs);
                    pk.z = f2b(acc[mi][ni][2] * qs); pk.w = f2b(acc[mi][ni][3] * qs);
                    *(ushort4*)(o_qv + ((size_t)b * 2048 + ngl) * 256 + ch) = pk;
                }
        } else {
            #pragma unroll
            for (int mi = 0; mi < 2; ++mi)
                #pragma unroll
                for (int ni = 0; ni < 2; ++ni) {
                    const int ngl = n0 + wn * 32 + ni * 16 + lr;
                    #pragma unroll
                    for (int r = 0; r < 4; ++r) {
                        const int m = m0 + wm * 32 + mi * 16 + lq * 4 + r;
                        const size_t ad = ((size_t)b * 256 + m) * 4096 + ngl;
                        outf[ad] = resid[ad] + acc[mi][ni][r];
                    }
                }
        }
        if (tt + 1 < 4) __syncthreads();
    }
}

// ---------------- MFMA attention: 1 wave per (b,g,h), VERIFIED K=32 MFMA only ----------------
// Stage Q/V/K into LDS [tok][16ch] via wave-uniform gload16 (16 calls, 1 barrier).
// Per qg (16 q): S = 16 ct tiles of mfma_16x16x32(qf,kf) with upper-K zeroed
// (exact round-2..13 pattern). Softmax fully in-wave: in-lane sum over ct +
// 4-step shfl_xor over lr (no psum LDS, no loop barriers). PV: 16-q contraction
// (slots lq*8+j for lq<2, zero otherwise); P relayout = 4 shfls + zero-select
// (round-13's verified 8-shfl pattern, halved). Q pre-scaled by SCALE*log2e.
template<int BR>
__global__ __launch_bounds__(64, 2) void k_attn(
    const bfu* __restrict__ Qv, const bfu* __restrict__ Kb,
    const bfu* __restrict__ Lp, bfu* __restrict__ cat) {
    const int bid = blockIdx.x;
    const int h = bid >> 8;            // h in HIGH bits: heads of a window share bid%8 (XCD)
    const int bg = bid & 255;
    const int b = bg >> 4, g = bg & 15;
    const int lane = threadIdx.x;
    const int lr = lane & 15, lq = lane >> 4;
    const int chQ = h * 16, chV = 128 + h * 16;
    const int chO = (BR == 0) ? h * 16 : 128 + h * 16;
    const bfu* Qb = Qv + (size_t)b * 2048 * 256;
    const bfu* Kg = Kb + (size_t)b * 4096 * 256 + chO;
    const bfu* Lg = Lp + (size_t)b * 4096 * 256 + chO;
    bfu* Cg = cat + (size_t)b * 4096 * 256 + chO;

    __shared__ __align__(16) bfu q_lds[2048];   // [128 tok][16 ch] 4 KB
    __shared__ __align__(16) bfu v_lds[2048];   // 4 KB
    __shared__ __align__(16) bfu k_lds[4096];   // [256 tok][16 ch] 8 KB

    // ---- stage (wave-uniform LDS dests; HW adds lane*16B; lane l covers
    // tok = c*32 + (l>>1), half = l&1 -> LDS byte c*1024 + l*16)
    {
        const int half = lane & 1;
        #pragma unroll
        for (int c = 0; c < 4; ++c) {
            const int tok = c * 32 + (lane >> 1);
            const int sp = (BR == 0) ? ((tok >> 2) * 64 + g * 4 + (tok & 3))
                                     : ((g * 4 + (tok >> 5)) * 32 + (tok & 31));
            gload16(Qb + (size_t)sp * 256 + chQ + half * 8, q_lds + c * 512);
            gload16(Qb + (size_t)sp * 256 + chV + half * 8, v_lds + c * 512);
        }
        #pragma unroll
        for (int c = 0; c < 8; ++c) {
            const int ktok = c * 32 + (lane >> 1);
            const int sp = (BR == 0) ? ((ktok >> 2) * 64 + g * 4 + (ktok & 3))
                                     : ((g * 4 + (ktok >> 6)) * 64 + (ktok & 63));
            gload16(Kg + (size_t)sp * 256 + half * 8, k_lds + c * 512);
        }
    }
    __syncthreads();   // drains gload16 (vmcnt) + LDS visibility

    const bf8v zero8 = {0, 0, 0, 0, 0, 0, 0, 0};
    const f32x4 zero4 = {0.f, 0.f, 0.f, 0.f};
    const bool hi = (lq >= 2);
    const int base = (lq & 1) * 32 + lr;

    f32x4 oacc[16];
    #pragma unroll
    for (int ct = 0; ct < 16; ++ct) {
        oacc[ct][0] = 0.f; oacc[ct][1] = 0.f; oacc[ct][2] = 0.f; oacc[ct][3] = 0.f;
    }

    for (int qg = 0; qg < 8; ++qg) {
        // Q A-frag: row q = qg*16+lr, d = lq*8+j (lq<2), upper-K zero
        const bf8v qf = hi ? zero8 : *(const bf8v*)(q_lds + (qg * 16 + lr) * 16 + lq * 8);
        // V^T A-frag: row d = lr, k-slot q = lq*8+j (only lq<2 slots matter; pf=0 above)
        bf8v vf;
        #pragma unroll
        for (int j = 0; j < 8; ++j)
            vf[j] = (short)v_lds[(qg * 16 + (lq & 1) * 8 + j) * 16 + lr];

        // S tiles: acc[ct] = S[q = qg*16 + lq*4+r][ktok = ct*16+lr]
        f32x4 acc[16];
        #pragma unroll
        for (int ct = 0; ct < 16; ++ct) {
            const bf8v kf = hi ? zero8 : *(const bf8v*)(k_lds + (ct * 16 + lr) * 16 + lq * 8);
            acc[ct] = __builtin_amdgcn_mfma_f32_16x16x32_bf16(qf, kf, zero4, 0, 0, 0);
        }

        // P = exp2(S_hat); row-sum in-lane over ct, then 4-step shfl over lr
        #pragma unroll
        for (int ct = 0; ct < 16; ++ct)
            #pragma unroll
            for (int r = 0; r < 4; ++r)
                acc[ct][r] = exp2f(acc[ct][r]);

        float rr[4];
        #pragma unroll
        for (int r = 0; r < 4; ++r) {
            float s = 0.f;
            #pragma unroll
            for (int ct = 0; ct < 16; ++ct) s += acc[ct][r];
            rr[r] = s;
        }
        #pragma unroll
        for (int s = 1; s <= 8; s <<= 1)
            #pragma unroll
            for (int r = 0; r < 4; ++r)
                rr[r] += __shfl_xor(rr[r], s);
        float inv[4];
        #pragma unroll
        for (int r = 0; r < 4; ++r) inv[r] = 1.0f / rr[r];

        // normalize + pack; relayout: dest (lq<2) slot j needs P[q=lq*8+j][lr]
        // = pk from lanes base (j<4) and base+16 (j>=4); lq>=2 slots zero.
        u32 pk[16][2];
        #pragma unroll
        for (int ct = 0; ct < 16; ++ct) {
            pk[ct][0] = cvtpk(acc[ct][0] * inv[0], acc[ct][1] * inv[1]);
            pk[ct][1] = cvtpk(acc[ct][2] * inv[2], acc[ct][3] * inv[3]);
        }
        #pragma unroll
        for (int ct = 0; ct < 16; ++ct) {
            const u32 a0 = (u32)__shfl((int)pk[ct][0], base);
            const u32 a1 = (u32)__shfl((int)pk[ct][1], base);
            const u32 a2 = (u32)__shfl((int)pk[ct][0], base + 16);
            const u32 a3 = (u32)__shfl((int)pk[ct][1], base + 16);
            u32x4 wd;
            wd[0] = hi ? 0u : a0; wd[1] = hi ? 0u : a1;
            wd[2] = hi ? 0u : a2; wd[3] = hi ? 0u : a3;
            const bf8v pf = __builtin_bit_cast(bf8v, wd);
            oacc[ct] = __builtin_amdgcn_mfma_f32_16x16x32_bf16(vf, pf, oacc[ct], 0, 0, 0);
        }
    }

    // epilogue: out^T[d][ktok]: d = lq*4+r, ktok = ct*16+lr; add lepe, store bf16
    #pragma unroll
    for (int ct = 0; ct < 16; ++ct) {
        const int ktok = ct * 16 + lr;
        const int sp = (BR == 0) ? ((ktok >> 2) * 64 + g * 4 + (ktok & 3))
                                 : ((g * 4 + (ktok >> 6)) * 64 + (ktok & 63));
        const size_t off = (size_t)sp * 256 + lq * 4;
        const ushort4 l4 = *(const ushort4*)(Lg + off);
        ushort4 o;
        o.x = f2b(oacc[ct][0] + bu2f(l4.x));
        o.y = f2b(oacc[ct][1] + bu2f(l4.y));
        o.z = f2b(oacc[ct][2] + bu2f(l4.z));
        o.w = f2b(oacc[ct][3] + bu2f(l4.w));
        *(ushort4*)(Cg + off) = o;
    }
}

extern "C" void kernel_launch(void* const* d_in, const int* in_sizes, int n_in,
                              void* d_out, int out_size, void* d_ws, size_t ws_size,
                              hipStream_t stream) {
    const float* fmap = (const float*)d_in[0];
    const float* Wqvh = (const float*)d_in[1];
    const float* Wqvv = (const float*)d_in[2];
    const float* Wk   = (const float*)d_in[3];
    const float* Wl   = (const float*)d_in[4];
    const float* Wp   = (const float*)d_in[5];
    float* out = (float*)d_out;
    char* ws = (char*)d_ws;

    // ws layout (exactly 128 MiB). cat aliases Fbf (Fbf dead after the qv GEMMs).
    bfu* Fbf   = (bfu*)(ws);                     // [16][4096][256] bf16 NHWC : 33,554,432 B
    bfu* cat   = Fbf;                            // alias (written by attn, after Fbf dead)
    bfu* k_all = (bfu*)(ws + 33554432);          // 33,554,432 B
    bfu* lepe  = (bfu*)(ws + 67108864);          // 33,554,432 B
    bfu* qvh   = (bfu*)(ws + 100663296);         // [16][2048][256] : 16,777,216 B
    bfu* qvv   = (bfu*)(ws + 117440512);         // 16,777,216 B -> 134,217,728

    // bf16 weights live in d_out (dead until proj rewrites it at the end).
    // NOTE: proj (k_gemm<3>) must NOT read from d_out — it writes d_out.
    bfu* Wkl = (bfu*)d_out;                      // [512][256] : 262,144 B
    bfu* Whr = (bfu*)((char*)d_out + 262144);    // [256][256] : 131,072 B
    bfu* Wvr = (bfu*)((char*)d_out + 393216);    // [256][256] : 131,072 B

    k_prep_f<<<dim3(64, 16), 256, 0, stream>>>(fmap, Fbf);
    k_prep_w<<<dim3(512), 256, 0, stream>>>(Wk, Wl, Wqvh, Wqvv, Wkl, Whr, Wvr);
    k_gemm<0><<<dim3(16, 4, 16), 512, 0, stream>>>(Wkl, nullptr, Fbf, k_all, lepe, nullptr, nullptr, nullptr);
    k_gemm<1><<<dim3(8, 2, 16), 512, 0, stream>>>(Whr, nullptr, Fbf, nullptr, nullptr, qvh, nullptr, nullptr);
    k_gemm<2><<<dim3(8, 2, 16), 512, 0, stream>>>(Wvr, nullptr, Fbf, nullptr, nullptr, qvv, nullptr, nullptr);
    k_attn<0><<<dim3(2048), 64, 0, stream>>>(qvh, k_all, lepe, cat);
    k_attn<1><<<dim3(2048), 64, 0, stream>>>(qvv, k_all, lepe, cat);
    k_gemm<3><<<dim3(16, 2, 16), 512, 0, stream>>>(nullptr, Wp, cat, nullptr, nullptr, nullptr, fmap, out);
}